// Round 8
// baseline (76.238 us; speedup 1.0000x reference)
//
#include <hip/hip_runtime.h>
#include <math.h>

#define EPSF 1e-5f
constexpr int NT  = 1024;
constexpr int ND  = 128;
constexpr int KIN = 19;
constexpr int H   = 256;
constexpr int L   = 128;

typedef __attribute__((ext_vector_type(8))) short short8;
typedef __attribute__((ext_vector_type(4))) float f32x4;

// packed fp32->bf16 (RNE), 2 elements per instruction
static __device__ inline unsigned cvt_pk_bf16(float lo, float hi) {
    unsigned r;
    asm("v_cvt_pk_bf16_f32 %0, %1, %2" : "=v"(r) : "v"(lo), "v"(hi));
    return r;
}

// ---------------------------------------------------------------------------
// Kernel F: features -> bf16 A-fragments in ws.
// Layout (uint4 units): feat[g*384 + mt*48 + kb*16 + r16], kb in 0..2 (48B/row).
// 2 g's per 256-block, one d per thread. Only 1 barrier (v0 combine).
// ---------------------------------------------------------------------------
__global__ __launch_bounds__(256) void k_feat(
    const float* __restrict__ x0, const float* __restrict__ x,
    const int*   __restrict__ Nv, const float* __restrict__ basis,
    const float* __restrict__ v,  uint4* __restrict__ featw)
{
    const int tid  = threadIdx.x;
    const int sub  = tid >> 7;           // which g in this block
    const int d    = tid & 127;
    const int w    = tid >> 6;
    const int lane = tid & 63;
    const int g    = blockIdx.x * 2 + sub;
    const int bidx = g >> 10;

    __shared__ float wsum[4][3];

    const float* xp = x + (size_t)g * (ND * 3);
    const float* vp = v + (size_t)g * (ND * 3);
    const float vx = vp[d*3+0], vy = vp[d*3+1], vz = vp[d*3+2];
    const float xx = xp[d*3+0], xy = xp[d*3+1], xz = xp[d*3+2];

    // per-wave v-sum, then combine the two waves of this g via LDS
    float sx = vx, sy = vy, sz = vz;
    #pragma unroll
    for (int m = 1; m < 64; m <<= 1) {
        sx += __shfl_xor(sx, m, 64);
        sy += __shfl_xor(sy, m, 64);
        sz += __shfl_xor(sz, m, 64);
    }
    if (lane == 0) { wsum[w][0] = sx; wsum[w][1] = sy; wsum[w][2] = sz; }
    __syncthreads();
    const float invd = 1.0f / (float)ND;
    const float v0x = (wsum[sub*2][0] + wsum[sub*2+1][0]) * invd;
    const float v0y = (wsum[sub*2][1] + wsum[sub*2+1][1]) * invd;
    const float v0z = (wsum[sub*2][2] + wsum[sub*2+1][2]) * invd;

    // block-uniform scalars (computed redundantly per thread)
    const float* bs = basis + bidx * 9;
    float fs[10];
    {
        const float ax = x0[g*3+0], ay = x0[g*3+1], az = x0[g*3+2];
        const float x0n = sqrtf(ax*ax + ay*ay + az*az) + EPSF;
        const float v0n = sqrtf(v0x*v0x + v0y*v0y + v0z*v0z) + EPSF;
        const float ix  = 1.f / x0n, iv0 = 1.f / v0n;
        fs[0] = log1pf((float)Nv[g]);
        fs[1] = x0n;
        fs[2] = (ax*bs[0] + ay*bs[1] + az*bs[2]) * ix;
        fs[3] = (ax*bs[3] + ay*bs[4] + az*bs[5]) * ix;
        fs[4] = (ax*bs[6] + ay*bs[7] + az*bs[8]) * ix;
        fs[5] = v0n;
        fs[6] = (v0x*bs[0] + v0y*bs[1] + v0z*bs[2]) * iv0;
        fs[7] = (v0x*bs[3] + v0y*bs[4] + v0z*bs[5]) * iv0;
        fs[8] = (v0x*bs[6] + v0y*bs[7] + v0z*bs[8]) * iv0;
        fs[9] = (ax*v0x + ay*v0y + az*v0z) * ix * iv0;
    }

    // per-d features
    const float cx = vx - v0x, cy = vy - v0y, cz = vz - v0z;
    const float xn = sqrtf(xx*xx + xy*xy + xz*xz) + EPSF;
    const float vn = sqrtf(cx*cx + cy*cy + cz*cz) + EPSF;
    const float ixn = 1.f/xn, ivn = 1.f/vn;
    float f[20];
    #pragma unroll
    for (int k = 0; k < 10; ++k) f[k] = fs[k];
    f[10] = xn;
    f[11] = (xx*bs[0] + xy*bs[1] + xz*bs[2]) * ixn;
    f[12] = (xx*bs[3] + xy*bs[4] + xz*bs[5]) * ixn;
    f[13] = (xx*bs[6] + xy*bs[7] + xz*bs[8]) * ixn;
    f[14] = vn;
    f[15] = (cx*bs[0] + cy*bs[1] + cz*bs[2]) * ivn;
    f[16] = (cx*bs[3] + cy*bs[4] + cz*bs[5]) * ivn;
    f[17] = (cx*bs[6] + cy*bs[7] + cz*bs[8]) * ivn;
    f[18] = (xx*cx + xy*cy + xz*cz) * ixn * ivn;
    f[19] = 1.0f;                          // bias-as-feature

    uint4 pk0, pk1, pk2;
    pk0.x = cvt_pk_bf16(f[0],  f[1]);  pk0.y = cvt_pk_bf16(f[2],  f[3]);
    pk0.z = cvt_pk_bf16(f[4],  f[5]);  pk0.w = cvt_pk_bf16(f[6],  f[7]);
    pk1.x = cvt_pk_bf16(f[8],  f[9]);  pk1.y = cvt_pk_bf16(f[10], f[11]);
    pk1.z = cvt_pk_bf16(f[12], f[13]); pk1.w = cvt_pk_bf16(f[14], f[15]);
    pk2.x = cvt_pk_bf16(f[16], f[17]); pk2.y = cvt_pk_bf16(f[18], f[19]);
    pk2.z = 0u; pk2.w = 0u;

    const int mt  = d >> 4;
    const int r16 = d & 15;
    uint4* base = featw + ((size_t)g * 384 + mt * 48 + r16);
    base[0]  = pk0;                        // kb=0 (k0..7)
    base[16] = pk1;                        // kb=1 (k8..15)
    base[32] = pk2;                        // kb=2 (k16..19,0,0,0,0)
}

// ---------------------------------------------------------------------------
// Kernel G: layer0 GEMM + leaky + mean-pool -> hm[4096][256].
// No LDS, no barriers. Wave-task = (g-pair, 64-col group).
// A-fragments read coalesced from global (lane<48; kb=3 is all-zero).
// ---------------------------------------------------------------------------
__global__ __launch_bounds__(256) void k_l0(
    const uint4* __restrict__ featw, const float* __restrict__ W0,
    const float* __restrict__ b0, float* __restrict__ hm_out)
{
    const int tid   = threadIdx.x;
    const int lane  = tid & 63;
    const int wid   = blockIdx.x * 4 + (tid >> 6);   // 0..8191
    const int cg    = wid & 3;                       // 64-col group
    const int gbase = (wid >> 2) * 2;                // 2 g's per wave

    // B fragments: k<19 = W0 row k; k==19 = b0; k>19 = 0
    short8 bfrag[4];
    {
        const int col16 = lane & 15;
        const int kb    = lane >> 4;
        #pragma unroll
        for (int nt = 0; nt < 4; ++nt) {
            const int col = cg * 64 + nt * 16 + col16;
            float fv[8];
            #pragma unroll
            for (int j = 0; j < 8; ++j) {
                const int k = kb * 8 + j;
                fv[j] = (k < KIN) ? W0[k * H + col] : ((k == KIN) ? b0[col] : 0.f);
            }
            uint4 pk;
            pk.x = cvt_pk_bf16(fv[0], fv[1]);
            pk.y = cvt_pk_bf16(fv[2], fv[3]);
            pk.z = cvt_pk_bf16(fv[4], fv[5]);
            pk.w = cvt_pk_bf16(fv[6], fv[7]);
            bfrag[nt] = *reinterpret_cast<short8*>(&pk);
        }
    }

    const f32x4 zc = {0.f, 0.f, 0.f, 0.f};
    const float invd = 1.0f / (float)ND;

    #pragma unroll 1
    for (int gi = 0; gi < 2; ++gi) {
        const int g = gbase + gi;
        f32x4 psum[4];
        #pragma unroll
        for (int nt = 0; nt < 4; ++nt)
            #pragma unroll
            for (int r = 0; r < 4; ++r) psum[nt][r] = 0.f;

        #pragma unroll
        for (int mt = 0; mt < 8; ++mt) {
            uint4 a4 = {0u, 0u, 0u, 0u};
            if (lane < 48)
                a4 = featw[(size_t)g * 384 + mt * 48 + lane];
            const short8 af = *reinterpret_cast<const short8*>(&a4);
            #pragma unroll
            for (int nt = 0; nt < 4; ++nt) {
                f32x4 d = __builtin_amdgcn_mfma_f32_16x16x32_bf16(af, bfrag[nt], zc, 0, 0, 0);
                #pragma unroll
                for (int r = 0; r < 4; ++r) {
                    const float a = d[r];
                    // leaky(a) = 0.505a + 0.495|a| (abs is a free VOP3 modifier)
                    psum[nt][r] = fmaf(0.505f, a, fmaf(0.495f, fabsf(a), psum[nt][r]));
                }
            }
        }

        #pragma unroll
        for (int nt = 0; nt < 4; ++nt) {
            float s4 = psum[nt][0] + psum[nt][1] + psum[nt][2] + psum[nt][3];
            s4 += __shfl_xor(s4, 16, 64);
            s4 += __shfl_xor(s4, 32, 64);
            if (lane < 16)
                hm_out[(size_t)g * H + cg * 64 + nt * 16 + lane] = s4 * invd;
        }
    }
}

// ---------------------------------------------------------------------------
// Kernel B: layers 1-2, 8 t per block (unchanged)
// ---------------------------------------------------------------------------
__global__ __launch_bounds__(256) void k_l12(
    const float* __restrict__ hm, const float* __restrict__ W1,
    const float* __restrict__ b1, const float* __restrict__ W2,
    const float* __restrict__ b2, float* __restrict__ out)
{
    const int tb  = blockIdx.x * 8;
    const int tid = threadIdx.x;
    __shared__ float hs[8][H];
    __shared__ float h1[8][H];

    {
        const float4* src = reinterpret_cast<const float4*>(hm + (size_t)tb * H);
        float4* dst = reinterpret_cast<float4*>(&hs[0][0]);
        #pragma unroll
        for (int i = 0; i < 2; ++i) dst[tid + i*256] = src[tid + i*256];
    }
    __syncthreads();

    {
        float acc[8];
        const float bb = b1[tid];
        #pragma unroll
        for (int t = 0; t < 8; ++t) acc[t] = bb;
        for (int k = 0; k < H; ++k) {
            const float w = W1[(size_t)k * H + tid];
            #pragma unroll
            for (int t = 0; t < 8; ++t) acc[t] = fmaf(hs[t][k], w, acc[t]);
        }
        #pragma unroll
        for (int t = 0; t < 8; ++t) {
            float a = acc[t];
            h1[t][tid] = (a > 0.f) ? a : 0.01f * a;
        }
    }
    __syncthreads();

    {
        const int n  = tid & 127;
        const int t0 = (tid >> 7) * 4;
        float acc[4];
        const float bb = b2[n];
        #pragma unroll
        for (int t = 0; t < 4; ++t) acc[t] = bb;
        for (int k = 0; k < H; ++k) {
            const float w = W2[(size_t)k * L + n];
            #pragma unroll
            for (int t = 0; t < 4; ++t) acc[t] = fmaf(h1[t0 + t][k], w, acc[t]);
        }
        #pragma unroll
        for (int t = 0; t < 4; ++t)
            out[(size_t)(tb + t0 + t) * L + n] = acc[t];
    }
}

extern "C" void kernel_launch(void* const* d_in, const int* in_sizes, int n_in,
                              void* d_out, int out_size, void* d_ws, size_t ws_size,
                              hipStream_t stream) {
    const float* x0    = (const float*)d_in[0];
    const float* x     = (const float*)d_in[1];
    const int*   Nv    = (const int*)  d_in[2];
    const float* basis = (const float*)d_in[3];
    const float* v     = (const float*)d_in[4];
    const float* W0    = (const float*)d_in[5];
    const float* b0    = (const float*)d_in[6];
    const float* W1    = (const float*)d_in[7];
    const float* b1    = (const float*)d_in[8];
    const float* W2    = (const float*)d_in[9];
    const float* b2    = (const float*)d_in[10];
    float* out = (float*)d_out;

    float* hm   = (float*)d_ws;                                  // 4 MB
    uint4* feat = (uint4*)((char*)d_ws + (size_t)4*1024*1024);   // 24 MB

    hipLaunchKernelGGL(k_feat, dim3(4 * NT / 2), dim3(256), 0, stream,
                       x0, x, Nv, basis, v, feat);
    hipLaunchKernelGGL(k_l0, dim3(4 * NT / 2), dim3(256), 0, stream,
                       feat, W0, b0, hm);
    hipLaunchKernelGGL(k_l12, dim3(4 * NT / 8), dim3(256), 0, stream,
                       hm, W1, b1, W2, b2, out);
}

// Round 9
// 64.058 us; speedup vs baseline: 1.1901x; 1.1901x over previous
//
#include <hip/hip_runtime.h>
#include <math.h>

#define EPSF 1e-5f
constexpr int NT  = 1024;
constexpr int ND  = 128;
constexpr int KIN = 19;
constexpr int H   = 256;
constexpr int L   = 128;

typedef __attribute__((ext_vector_type(8))) short short8;
typedef __attribute__((ext_vector_type(4))) float f32x4;

// packed fp32->bf16 (RNE), 2 elements per instruction
static __device__ inline unsigned cvt_pk_bf16(float lo, float hi) {
    unsigned r;
    asm("v_cvt_pk_bf16_f32 %0, %1, %2" : "=v"(r) : "v"(lo), "v"(hi));
    return r;
}

// ---------------------------------------------------------------------------
// Kernel F: features -> bf16 A-fragments in ws.
// Layout (uint4 units): feat[g*384 + mt*48 + kb*16 + r16], kb in 0..2 (48B/row).
// 2 g's per 256-block, one d per thread. Eager pair-packing keeps VGPR low.
// ---------------------------------------------------------------------------
__global__ __launch_bounds__(256) void k_feat(
    const float* __restrict__ x0, const float* __restrict__ x,
    const int*   __restrict__ Nv, const float* __restrict__ basis,
    const float* __restrict__ v,  uint4* __restrict__ featw)
{
    const int tid  = threadIdx.x;
    const int sub  = tid >> 7;           // which g in this block
    const int d    = tid & 127;
    const int w    = tid >> 6;
    const int lane = tid & 63;
    const int g    = blockIdx.x * 2 + sub;
    const int bidx = g >> 10;

    __shared__ float wsum[4][3];

    const float* xp = x + (size_t)g * (ND * 3);
    const float* vp = v + (size_t)g * (ND * 3);
    const float vx = vp[d*3+0], vy = vp[d*3+1], vz = vp[d*3+2];
    const float xx = xp[d*3+0], xy = xp[d*3+1], xz = xp[d*3+2];

    // per-wave v-sum, then combine the two waves of this g via LDS
    float sx = vx, sy = vy, sz = vz;
    #pragma unroll
    for (int m = 1; m < 64; m <<= 1) {
        sx += __shfl_xor(sx, m, 64);
        sy += __shfl_xor(sy, m, 64);
        sz += __shfl_xor(sz, m, 64);
    }
    if (lane == 0) { wsum[w][0] = sx; wsum[w][1] = sy; wsum[w][2] = sz; }
    __syncthreads();
    const float invd = 1.0f / (float)ND;
    const float v0x = (wsum[sub*2][0] + wsum[sub*2+1][0]) * invd;
    const float v0y = (wsum[sub*2][1] + wsum[sub*2+1][1]) * invd;
    const float v0z = (wsum[sub*2][2] + wsum[sub*2+1][2]) * invd;

    const float* bs = basis + bidx * 9;
    const float b0c = bs[0], b1c = bs[1], b2c = bs[2];
    const float b3c = bs[3], b4c = bs[4], b5c = bs[5];
    const float b6c = bs[6], b7c = bs[7], b8c = bs[8];

    // ---- block-uniform scalar feats, packed eagerly (u0..u4) ----
    unsigned u0, u1, u2, u3, u4;
    {
        const float ax = x0[g*3+0], ay = x0[g*3+1], az = x0[g*3+2];
        const float x0n = sqrtf(ax*ax + ay*ay + az*az) + EPSF;
        const float v0n = sqrtf(v0x*v0x + v0y*v0y + v0z*v0z) + EPSF;
        const float ix  = 1.f / x0n, iv0 = 1.f / v0n;
        u0 = cvt_pk_bf16(log1pf((float)Nv[g]), x0n);
        u1 = cvt_pk_bf16((ax*b0c + ay*b1c + az*b2c) * ix,
                         (ax*b3c + ay*b4c + az*b5c) * ix);
        u2 = cvt_pk_bf16((ax*b6c + ay*b7c + az*b8c) * ix, v0n);
        u3 = cvt_pk_bf16((v0x*b0c + v0y*b1c + v0z*b2c) * iv0,
                         (v0x*b3c + v0y*b4c + v0z*b5c) * iv0);
        u4 = cvt_pk_bf16((v0x*b6c + v0y*b7c + v0z*b8c) * iv0,
                         (ax*v0x + ay*v0y + az*v0z) * ix * iv0);
    }

    // ---- per-d feats, packed eagerly (u5..u9) ----
    unsigned u5, u6, u7, u8, u9;
    {
        const float cx = vx - v0x, cy = vy - v0y, cz = vz - v0z;
        const float xn = sqrtf(xx*xx + xy*xy + xz*xz) + EPSF;
        const float vn = sqrtf(cx*cx + cy*cy + cz*cz) + EPSF;
        const float ixn = 1.f/xn, ivn = 1.f/vn;
        u5 = cvt_pk_bf16(xn, (xx*b0c + xy*b1c + xz*b2c) * ixn);
        u6 = cvt_pk_bf16((xx*b3c + xy*b4c + xz*b5c) * ixn,
                         (xx*b6c + xy*b7c + xz*b8c) * ixn);
        u7 = cvt_pk_bf16(vn, (cx*b0c + cy*b1c + cz*b2c) * ivn);
        u8 = cvt_pk_bf16((cx*b3c + cy*b4c + cz*b5c) * ivn,
                         (cx*b6c + cy*b7c + cz*b8c) * ivn);
        u9 = cvt_pk_bf16((xx*cx + xy*cy + xz*cz) * ixn * ivn, 1.0f);
    }

    const int mt  = d >> 4;
    const int r16 = d & 15;
    uint4* base = featw + ((size_t)g * 384 + mt * 48 + r16);
    base[0]  = uint4{u0, u1, u2, u3};      // kb=0 (k0..7)
    base[16] = uint4{u4, u5, u6, u7};      // kb=1 (k8..15)
    base[32] = uint4{u8, u9, 0u, 0u};      // kb=2 (k16..19,0,0,0,0)
}

// ---------------------------------------------------------------------------
// Kernel G: layer0 GEMM + leaky + mean-pool -> hm[4096][256].
// No LDS, no barriers. Wave-task = (g-pair, 64-col group).
// Scalar accumulators + unroll-2 mt keep VGPR <= 64 (8 waves/SIMD).
// ---------------------------------------------------------------------------
__global__ __launch_bounds__(256) void k_l0(
    const uint4* __restrict__ featw, const float* __restrict__ W0,
    const float* __restrict__ b0, float* __restrict__ hm_out)
{
    const int tid   = threadIdx.x;
    const int lane  = tid & 63;
    const int wid   = blockIdx.x * 4 + (tid >> 6);   // 0..8191
    const int cg    = wid & 3;                       // 64-col group
    const int gbase = (wid >> 2) * 2;                // 2 g's per wave

    // B fragments: k<19 = W0 row k; k==19 = b0; k>19 = 0 (pairwise build)
    short8 bfrag[4];
    {
        const int col16 = lane & 15;
        const int kb    = lane >> 4;
        #pragma unroll
        for (int nt = 0; nt < 4; ++nt) {
            const int col = cg * 64 + nt * 16 + col16;
            uint4 pk;
            #pragma unroll
            for (int jj = 0; jj < 4; ++jj) {
                const int k0 = kb * 8 + 2*jj;
                const int k1 = k0 + 1;
                const float a = (k0 < KIN) ? W0[k0 * H + col]
                               : ((k0 == KIN) ? b0[col] : 0.f);
                const float b = (k1 < KIN) ? W0[k1 * H + col]
                               : ((k1 == KIN) ? b0[col] : 0.f);
                (&pk.x)[jj] = cvt_pk_bf16(a, b);
            }
            bfrag[nt] = *reinterpret_cast<short8*>(&pk);
        }
    }

    const f32x4 zc = {0.f, 0.f, 0.f, 0.f};
    const float invd = 1.0f / (float)ND;

    #pragma unroll 1
    for (int gi = 0; gi < 2; ++gi) {
        const int g = gbase + gi;
        float s0 = 0.f, s1 = 0.f, s2 = 0.f, s3 = 0.f;

        #pragma unroll 2
        for (int mt = 0; mt < 8; ++mt) {
            uint4 a4 = {0u, 0u, 0u, 0u};
            if (lane < 48)
                a4 = featw[(size_t)g * 384 + mt * 48 + lane];
            const short8 af = *reinterpret_cast<const short8*>(&a4);
            {
                f32x4 dd = __builtin_amdgcn_mfma_f32_16x16x32_bf16(af, bfrag[0], zc, 0, 0, 0);
                #pragma unroll
                for (int r = 0; r < 4; ++r)
                    s0 = fmaf(0.505f, dd[r], fmaf(0.495f, fabsf(dd[r]), s0));
            }
            {
                f32x4 dd = __builtin_amdgcn_mfma_f32_16x16x32_bf16(af, bfrag[1], zc, 0, 0, 0);
                #pragma unroll
                for (int r = 0; r < 4; ++r)
                    s1 = fmaf(0.505f, dd[r], fmaf(0.495f, fabsf(dd[r]), s1));
            }
            {
                f32x4 dd = __builtin_amdgcn_mfma_f32_16x16x32_bf16(af, bfrag[2], zc, 0, 0, 0);
                #pragma unroll
                for (int r = 0; r < 4; ++r)
                    s2 = fmaf(0.505f, dd[r], fmaf(0.495f, fabsf(dd[r]), s2));
            }
            {
                f32x4 dd = __builtin_amdgcn_mfma_f32_16x16x32_bf16(af, bfrag[3], zc, 0, 0, 0);
                #pragma unroll
                for (int r = 0; r < 4; ++r)
                    s3 = fmaf(0.505f, dd[r], fmaf(0.495f, fabsf(dd[r]), s3));
            }
        }

        // epilogue: reduce across lane groups (rows), write hm
        float sv[4] = {s0, s1, s2, s3};
        #pragma unroll
        for (int nt = 0; nt < 4; ++nt) {
            float s4 = sv[nt];
            s4 += __shfl_xor(s4, 16, 64);
            s4 += __shfl_xor(s4, 32, 64);
            if (lane < 16)
                hm_out[(size_t)g * H + cg * 64 + nt * 16 + lane] = s4 * invd;
        }
    }
}

// ---------------------------------------------------------------------------
// Kernel B: layers 1-2, 8 t per block (unchanged)
// ---------------------------------------------------------------------------
__global__ __launch_bounds__(256) void k_l12(
    const float* __restrict__ hm, const float* __restrict__ W1,
    const float* __restrict__ b1, const float* __restrict__ W2,
    const float* __restrict__ b2, float* __restrict__ out)
{
    const int tb  = blockIdx.x * 8;
    const int tid = threadIdx.x;
    __shared__ float hs[8][H];
    __shared__ float h1[8][H];

    {
        const float4* src = reinterpret_cast<const float4*>(hm + (size_t)tb * H);
        float4* dst = reinterpret_cast<float4*>(&hs[0][0]);
        #pragma unroll
        for (int i = 0; i < 2; ++i) dst[tid + i*256] = src[tid + i*256];
    }
    __syncthreads();

    {
        float acc[8];
        const float bb = b1[tid];
        #pragma unroll
        for (int t = 0; t < 8; ++t) acc[t] = bb;
        for (int k = 0; k < H; ++k) {
            const float w = W1[(size_t)k * H + tid];
            #pragma unroll
            for (int t = 0; t < 8; ++t) acc[t] = fmaf(hs[t][k], w, acc[t]);
        }
        #pragma unroll
        for (int t = 0; t < 8; ++t) {
            float a = acc[t];
            h1[t][tid] = (a > 0.f) ? a : 0.01f * a;
        }
    }
    __syncthreads();

    {
        const int n  = tid & 127;
        const int t0 = (tid >> 7) * 4;
        float acc[4];
        const float bb = b2[n];
        #pragma unroll
        for (int t = 0; t < 4; ++t) acc[t] = bb;
        for (int k = 0; k < H; ++k) {
            const float w = W2[(size_t)k * L + n];
            #pragma unroll
            for (int t = 0; t < 4; ++t) acc[t] = fmaf(h1[t0 + t][k], w, acc[t]);
        }
        #pragma unroll
        for (int t = 0; t < 4; ++t)
            out[(size_t)(tb + t0 + t) * L + n] = acc[t];
    }
}

extern "C" void kernel_launch(void* const* d_in, const int* in_sizes, int n_in,
                              void* d_out, int out_size, void* d_ws, size_t ws_size,
                              hipStream_t stream) {
    const float* x0    = (const float*)d_in[0];
    const float* x     = (const float*)d_in[1];
    const int*   Nv    = (const int*)  d_in[2];
    const float* basis = (const float*)d_in[3];
    const float* v     = (const float*)d_in[4];
    const float* W0    = (const float*)d_in[5];
    const float* b0    = (const float*)d_in[6];
    const float* W1    = (const float*)d_in[7];
    const float* b1    = (const float*)d_in[8];
    const float* W2    = (const float*)d_in[9];
    const float* b2    = (const float*)d_in[10];
    float* out = (float*)d_out;

    float* hm   = (float*)d_ws;                                  // 4 MB
    uint4* feat = (uint4*)((char*)d_ws + (size_t)4*1024*1024);   // 24 MB

    hipLaunchKernelGGL(k_feat, dim3(4 * NT / 2), dim3(256), 0, stream,
                       x0, x, Nv, basis, v, feat);
    hipLaunchKernelGGL(k_l0, dim3(4 * NT / 2), dim3(256), 0, stream,
                       feat, W0, b0, hm);
    hipLaunchKernelGGL(k_l12, dim3(4 * NT / 8), dim3(256), 0, stream,
                       hm, W1, b1, W2, b2, out);
}

// Round 10
// 48.777 us; speedup vs baseline: 1.5630x; 1.3133x over previous
//
#include <hip/hip_runtime.h>
#include <math.h>

#define EPSF 1e-5f
constexpr int NT  = 1024;
constexpr int ND  = 128;
constexpr int KIN = 19;
constexpr int H   = 256;
constexpr int L   = 128;

typedef __attribute__((ext_vector_type(8))) short short8;
typedef __attribute__((ext_vector_type(4))) float f32x4;

// packed fp32->bf16 (RNE), 2 elements per instruction
static __device__ inline unsigned cvt_pk_bf16(float lo, float hi) {
    unsigned r;
    asm("v_cvt_pk_bf16_f32 %0, %1, %2" : "=v"(r) : "v"(lo), "v"(hi));
    return r;
}

// ---------------------------------------------------------------------------
// Fused kernel A: 2 g's per 256-thread block (2048 blocks = 8192 waves).
// Phase 1: features, 1 d per thread -> bf16 A-fragments in LDS.
// Phase 2: each wave: bfrag for its 64-col group, then MFMA over both g's
//          (bfrag amortized x2), leaky+pool fused, scalar accumulators.
// ---------------------------------------------------------------------------
__global__ __launch_bounds__(256) void k_fused(
    const float* __restrict__ x0, const float* __restrict__ x,
    const int*   __restrict__ Nv, const float* __restrict__ basis,
    const float* __restrict__ v,  const float* __restrict__ W0,
    const float* __restrict__ b0, float* __restrict__ hm_out)
{
    const int tid  = threadIdx.x;
    const int lane = tid & 63;
    const int w    = tid >> 6;            // wave 0..3
    const int g2   = blockIdx.x * 2;

    __shared__ __align__(16) ushort featb[2 * 512 * 8];   // 16 KB
    __shared__ float psh[2][2][3];                        // per-g half-sums

    // ---- Phase 1: features (1 d per thread) ----
    {
        const int sub  = tid >> 7;        // which g of the pair
        const int d    = tid & 127;
        const int g    = g2 + sub;
        const int bidx = g >> 10;

        const float* xp = x + (size_t)g * (ND * 3);
        const float* vp = v + (size_t)g * (ND * 3);
        const float vx = vp[d*3+0], vy = vp[d*3+1], vz = vp[d*3+2];
        const float xx = xp[d*3+0], xy = xp[d*3+1], xz = xp[d*3+2];

        // wave-local 64-sum (each wave covers one 64-d half of one g)
        float sx = vx, sy = vy, sz = vz;
        #pragma unroll
        for (int m = 1; m < 64; m <<= 1) {
            sx += __shfl_xor(sx, m, 64);
            sy += __shfl_xor(sy, m, 64);
            sz += __shfl_xor(sz, m, 64);
        }
        if (lane == 0) {
            psh[sub][w & 1][0] = sx;
            psh[sub][w & 1][1] = sy;
            psh[sub][w & 1][2] = sz;
        }
        __syncthreads();
        const float invd = 1.0f / (float)ND;
        const float v0x = (psh[sub][0][0] + psh[sub][1][0]) * invd;
        const float v0y = (psh[sub][0][1] + psh[sub][1][1]) * invd;
        const float v0z = (psh[sub][0][2] + psh[sub][1][2]) * invd;

        const float* bs = basis + bidx * 9;
        const float b0c = bs[0], b1c = bs[1], b2c = bs[2];
        const float b3c = bs[3], b4c = bs[4], b5c = bs[5];
        const float b6c = bs[6], b7c = bs[7], b8c = bs[8];

        unsigned u0, u1, u2, u3, u4;
        {
            const float ax = x0[g*3+0], ay = x0[g*3+1], az = x0[g*3+2];
            const float x0n = sqrtf(ax*ax + ay*ay + az*az) + EPSF;
            const float v0n = sqrtf(v0x*v0x + v0y*v0y + v0z*v0z) + EPSF;
            const float ix  = 1.f / x0n, iv0 = 1.f / v0n;
            u0 = cvt_pk_bf16(log1pf((float)Nv[g]), x0n);
            u1 = cvt_pk_bf16((ax*b0c + ay*b1c + az*b2c) * ix,
                             (ax*b3c + ay*b4c + az*b5c) * ix);
            u2 = cvt_pk_bf16((ax*b6c + ay*b7c + az*b8c) * ix, v0n);
            u3 = cvt_pk_bf16((v0x*b0c + v0y*b1c + v0z*b2c) * iv0,
                             (v0x*b3c + v0y*b4c + v0z*b5c) * iv0);
            u4 = cvt_pk_bf16((v0x*b6c + v0y*b7c + v0z*b8c) * iv0,
                             (ax*v0x + ay*v0y + az*v0z) * ix * iv0);
        }
        unsigned u5, u6, u7, u8, u9;
        {
            const float cx = vx - v0x, cy = vy - v0y, cz = vz - v0z;
            const float xn = sqrtf(xx*xx + xy*xy + xz*xz) + EPSF;
            const float vn = sqrtf(cx*cx + cy*cy + cz*cz) + EPSF;
            const float ixn = 1.f/xn, ivn = 1.f/vn;
            u5 = cvt_pk_bf16(xn, (xx*b0c + xy*b1c + xz*b2c) * ixn);
            u6 = cvt_pk_bf16((xx*b3c + xy*b4c + xz*b5c) * ixn,
                             (xx*b6c + xy*b7c + xz*b8c) * ixn);
            u7 = cvt_pk_bf16(vn, (cx*b0c + cy*b1c + cz*b2c) * ivn);
            u8 = cvt_pk_bf16((cx*b3c + cy*b4c + cz*b5c) * ivn,
                             (cx*b6c + cy*b7c + cz*b8c) * ivn);
            u9 = cvt_pk_bf16((xx*cx + xy*cy + xz*cz) * ixn * ivn, 1.0f);
        }

        const int mt  = d >> 4;
        const int r16 = d & 15;
        uint4* base = reinterpret_cast<uint4*>(
            &featb[((sub << 9) + (mt << 6) + r16) * 8]);
        base[0]  = uint4{u0, u1, u2, u3};          // kb=0 (k0..7)
        base[16] = uint4{u4, u5, u6, u7};          // kb=1 (k8..15)
        base[32] = uint4{u8, u9, 0u, 0u};          // kb=2 (k16..19,0,0)
        base[48] = uint4{0u, 0u, 0u, 0u};          // kb=3 (zero)
    }
    __syncthreads();

    // ---- Phase 2: B fragments for this wave's 64-col group ----
    short8 bfrag[4];
    {
        const int col16 = lane & 15;
        const int kb    = lane >> 4;
        #pragma unroll
        for (int nt = 0; nt < 4; ++nt) {
            const int col = w * 64 + nt * 16 + col16;
            uint4 pk;
            #pragma unroll
            for (int jj = 0; jj < 4; ++jj) {
                const int k0 = kb * 8 + 2*jj;
                const int k1 = k0 + 1;
                const float a = (k0 < KIN) ? W0[k0 * H + col]
                               : ((k0 == KIN) ? b0[col] : 0.f);
                const float b = (k1 < KIN) ? W0[k1 * H + col]
                               : ((k1 == KIN) ? b0[col] : 0.f);
                (&pk.x)[jj] = cvt_pk_bf16(a, b);
            }
            bfrag[nt] = *reinterpret_cast<short8*>(&pk);
        }
    }

    // ---- MFMA over both g's (bfrag amortized), leaky+pool fused ----
    const f32x4 zc = {0.f, 0.f, 0.f, 0.f};
    const float invd = 1.0f / (float)ND;

    #pragma unroll 1
    for (int gi = 0; gi < 2; ++gi) {
        float s0 = 0.f, s1 = 0.f, s2 = 0.f, s3 = 0.f;

        #pragma unroll 2
        for (int mt = 0; mt < 8; ++mt) {
            const short8 af = *reinterpret_cast<const short8*>(
                &featb[((gi << 9) + (mt << 6) + lane) * 8]);
            {
                f32x4 dd = __builtin_amdgcn_mfma_f32_16x16x32_bf16(af, bfrag[0], zc, 0, 0, 0);
                #pragma unroll
                for (int r = 0; r < 4; ++r)
                    s0 = fmaf(0.505f, dd[r], fmaf(0.495f, fabsf(dd[r]), s0));
            }
            {
                f32x4 dd = __builtin_amdgcn_mfma_f32_16x16x32_bf16(af, bfrag[1], zc, 0, 0, 0);
                #pragma unroll
                for (int r = 0; r < 4; ++r)
                    s1 = fmaf(0.505f, dd[r], fmaf(0.495f, fabsf(dd[r]), s1));
            }
            {
                f32x4 dd = __builtin_amdgcn_mfma_f32_16x16x32_bf16(af, bfrag[2], zc, 0, 0, 0);
                #pragma unroll
                for (int r = 0; r < 4; ++r)
                    s2 = fmaf(0.505f, dd[r], fmaf(0.495f, fabsf(dd[r]), s2));
            }
            {
                f32x4 dd = __builtin_amdgcn_mfma_f32_16x16x32_bf16(af, bfrag[3], zc, 0, 0, 0);
                #pragma unroll
                for (int r = 0; r < 4; ++r)
                    s3 = fmaf(0.505f, dd[r], fmaf(0.495f, fabsf(dd[r]), s3));
            }
        }

        float sv[4] = {s0, s1, s2, s3};
        #pragma unroll
        for (int nt = 0; nt < 4; ++nt) {
            float s4 = sv[nt];
            s4 += __shfl_xor(s4, 16, 64);
            s4 += __shfl_xor(s4, 32, 64);
            if (lane < 16)
                hm_out[(size_t)(g2 + gi) * H + w * 64 + nt * 16 + lane] = s4 * invd;
        }
    }
}

// ---------------------------------------------------------------------------
// Kernel B: layers 1-2, 8 t per block (unchanged)
// ---------------------------------------------------------------------------
__global__ __launch_bounds__(256) void k_l12(
    const float* __restrict__ hm, const float* __restrict__ W1,
    const float* __restrict__ b1, const float* __restrict__ W2,
    const float* __restrict__ b2, float* __restrict__ out)
{
    const int tb  = blockIdx.x * 8;
    const int tid = threadIdx.x;
    __shared__ float hs[8][H];
    __shared__ float h1[8][H];

    {
        const float4* src = reinterpret_cast<const float4*>(hm + (size_t)tb * H);
        float4* dst = reinterpret_cast<float4*>(&hs[0][0]);
        #pragma unroll
        for (int i = 0; i < 2; ++i) dst[tid + i*256] = src[tid + i*256];
    }
    __syncthreads();

    {
        float acc[8];
        const float bb = b1[tid];
        #pragma unroll
        for (int t = 0; t < 8; ++t) acc[t] = bb;
        for (int k = 0; k < H; ++k) {
            const float w = W1[(size_t)k * H + tid];
            #pragma unroll
            for (int t = 0; t < 8; ++t) acc[t] = fmaf(hs[t][k], w, acc[t]);
        }
        #pragma unroll
        for (int t = 0; t < 8; ++t) {
            float a = acc[t];
            h1[t][tid] = (a > 0.f) ? a : 0.01f * a;
        }
    }
    __syncthreads();

    {
        const int n  = tid & 127;
        const int t0 = (tid >> 7) * 4;
        float acc[4];
        const float bb = b2[n];
        #pragma unroll
        for (int t = 0; t < 4; ++t) acc[t] = bb;
        for (int k = 0; k < H; ++k) {
            const float w = W2[(size_t)k * L + n];
            #pragma unroll
            for (int t = 0; t < 4; ++t) acc[t] = fmaf(h1[t0 + t][k], w, acc[t]);
        }
        #pragma unroll
        for (int t = 0; t < 4; ++t)
            out[(size_t)(tb + t0 + t) * L + n] = acc[t];
    }
}

extern "C" void kernel_launch(void* const* d_in, const int* in_sizes, int n_in,
                              void* d_out, int out_size, void* d_ws, size_t ws_size,
                              hipStream_t stream) {
    const float* x0    = (const float*)d_in[0];
    const float* x     = (const float*)d_in[1];
    const int*   Nv    = (const int*)  d_in[2];
    const float* basis = (const float*)d_in[3];
    const float* v     = (const float*)d_in[4];
    const float* W0    = (const float*)d_in[5];
    const float* b0    = (const float*)d_in[6];
    const float* W1    = (const float*)d_in[7];
    const float* b1    = (const float*)d_in[8];
    const float* W2    = (const float*)d_in[9];
    const float* b2    = (const float*)d_in[10];
    float* out = (float*)d_out;
    float* hm  = (float*)d_ws;          // 4096*256*4 = 4 MB

    hipLaunchKernelGGL(k_fused, dim3(4 * NT / 2), dim3(256), 0, stream,
                       x0, x, Nv, basis, v, W0, b0, hm);
    hipLaunchKernelGGL(k_l12, dim3(4 * NT / 8), dim3(256), 0, stream,
                       hm, W1, b1, W2, b2, out);
}

// Round 11
// 48.668 us; speedup vs baseline: 1.5665x; 1.0022x over previous
//
#include <hip/hip_runtime.h>
#include <math.h>

#define EPSF 1e-5f
constexpr int NT  = 1024;
constexpr int ND  = 128;
constexpr int KIN = 19;
constexpr int H   = 256;
constexpr int L   = 128;

typedef __attribute__((ext_vector_type(8))) short short8;
typedef __attribute__((ext_vector_type(4))) float f32x4;

// packed fp32->bf16 (RNE), 2 elements per instruction
static __device__ inline unsigned cvt_pk_bf16(float lo, float hi) {
    unsigned r;
    asm("v_cvt_pk_bf16_f32 %0, %1, %2" : "=v"(r) : "v"(lo), "v"(hi));
    return r;
}

// ---------------------------------------------------------------------------
// Fused kernel A: 2 g's per 256-thread block (2048 blocks = 8192 waves).
// __launch_bounds__(256,4): forces the 64-VGPR bracket (R4 evidence) so 8
// blocks/CU become resident; this kernel's live set (~55) should fit w/o spill.
// ---------------------------------------------------------------------------
__global__ __launch_bounds__(256, 4) void k_fused(
    const float* __restrict__ x0, const float* __restrict__ x,
    const int*   __restrict__ Nv, const float* __restrict__ basis,
    const float* __restrict__ v,  const float* __restrict__ W0,
    const float* __restrict__ b0, float* __restrict__ hm_out)
{
    const int tid  = threadIdx.x;
    const int lane = tid & 63;
    const int w    = tid >> 6;            // wave 0..3
    const int g2   = blockIdx.x * 2;

    __shared__ __align__(16) ushort featb[2 * 512 * 8];   // 16 KB
    __shared__ float psh[2][2][3];                        // per-g half-sums

    // ---- Phase 1: features (1 d per thread) ----
    {
        const int sub  = tid >> 7;        // which g of the pair
        const int d    = tid & 127;
        const int g    = g2 + sub;
        const int bidx = g >> 10;

        const float* xp = x + (size_t)g * (ND * 3);
        const float* vp = v + (size_t)g * (ND * 3);
        const float vx = vp[d*3+0], vy = vp[d*3+1], vz = vp[d*3+2];
        const float xx = xp[d*3+0], xy = xp[d*3+1], xz = xp[d*3+2];

        // wave-local 64-sum (each wave covers one 64-d half of one g)
        float sx = vx, sy = vy, sz = vz;
        #pragma unroll
        for (int m = 1; m < 64; m <<= 1) {
            sx += __shfl_xor(sx, m, 64);
            sy += __shfl_xor(sy, m, 64);
            sz += __shfl_xor(sz, m, 64);
        }
        if (lane == 0) {
            psh[sub][w & 1][0] = sx;
            psh[sub][w & 1][1] = sy;
            psh[sub][w & 1][2] = sz;
        }
        __syncthreads();
        const float invd = 1.0f / (float)ND;
        const float v0x = (psh[sub][0][0] + psh[sub][1][0]) * invd;
        const float v0y = (psh[sub][0][1] + psh[sub][1][1]) * invd;
        const float v0z = (psh[sub][0][2] + psh[sub][1][2]) * invd;

        const float* bs = basis + bidx * 9;
        const float b0c = bs[0], b1c = bs[1], b2c = bs[2];
        const float b3c = bs[3], b4c = bs[4], b5c = bs[5];
        const float b6c = bs[6], b7c = bs[7], b8c = bs[8];

        unsigned u0, u1, u2, u3, u4;
        {
            const float ax = x0[g*3+0], ay = x0[g*3+1], az = x0[g*3+2];
            const float x0n = sqrtf(ax*ax + ay*ay + az*az) + EPSF;
            const float v0n = sqrtf(v0x*v0x + v0y*v0y + v0z*v0z) + EPSF;
            const float ix  = 1.f / x0n, iv0 = 1.f / v0n;
            u0 = cvt_pk_bf16(log1pf((float)Nv[g]), x0n);
            u1 = cvt_pk_bf16((ax*b0c + ay*b1c + az*b2c) * ix,
                             (ax*b3c + ay*b4c + az*b5c) * ix);
            u2 = cvt_pk_bf16((ax*b6c + ay*b7c + az*b8c) * ix, v0n);
            u3 = cvt_pk_bf16((v0x*b0c + v0y*b1c + v0z*b2c) * iv0,
                             (v0x*b3c + v0y*b4c + v0z*b5c) * iv0);
            u4 = cvt_pk_bf16((v0x*b6c + v0y*b7c + v0z*b8c) * iv0,
                             (ax*v0x + ay*v0y + az*v0z) * ix * iv0);
        }
        unsigned u5, u6, u7, u8, u9;
        {
            const float cx = vx - v0x, cy = vy - v0y, cz = vz - v0z;
            const float xn = sqrtf(xx*xx + xy*xy + xz*xz) + EPSF;
            const float vn = sqrtf(cx*cx + cy*cy + cz*cz) + EPSF;
            const float ixn = 1.f/xn, ivn = 1.f/vn;
            u5 = cvt_pk_bf16(xn, (xx*b0c + xy*b1c + xz*b2c) * ixn);
            u6 = cvt_pk_bf16((xx*b3c + xy*b4c + xz*b5c) * ixn,
                             (xx*b6c + xy*b7c + xz*b8c) * ixn);
            u7 = cvt_pk_bf16(vn, (cx*b0c + cy*b1c + cz*b2c) * ivn);
            u8 = cvt_pk_bf16((cx*b3c + cy*b4c + cz*b5c) * ivn,
                             (cx*b6c + cy*b7c + cz*b8c) * ivn);
            u9 = cvt_pk_bf16((xx*cx + xy*cy + xz*cz) * ixn * ivn, 1.0f);
        }

        const int mt  = d >> 4;
        const int r16 = d & 15;
        uint4* base = reinterpret_cast<uint4*>(
            &featb[((sub << 9) + (mt << 6) + r16) * 8]);
        base[0]  = uint4{u0, u1, u2, u3};          // kb=0 (k0..7)
        base[16] = uint4{u4, u5, u6, u7};          // kb=1 (k8..15)
        base[32] = uint4{u8, u9, 0u, 0u};          // kb=2 (k16..19,0,0)
        base[48] = uint4{0u, 0u, 0u, 0u};          // kb=3 (zero)
    }
    __syncthreads();

    // ---- Phase 2: B fragments for this wave's 64-col group ----
    short8 bfrag[4];
    {
        const int col16 = lane & 15;
        const int kb    = lane >> 4;
        #pragma unroll
        for (int nt = 0; nt < 4; ++nt) {
            const int col = w * 64 + nt * 16 + col16;
            uint4 pk;
            #pragma unroll
            for (int jj = 0; jj < 4; ++jj) {
                const int k0 = kb * 8 + 2*jj;
                const int k1 = k0 + 1;
                const float a = (k0 < KIN) ? W0[k0 * H + col]
                               : ((k0 == KIN) ? b0[col] : 0.f);
                const float b = (k1 < KIN) ? W0[k1 * H + col]
                               : ((k1 == KIN) ? b0[col] : 0.f);
                (&pk.x)[jj] = cvt_pk_bf16(a, b);
            }
            bfrag[nt] = *reinterpret_cast<short8*>(&pk);
        }
    }

    // ---- MFMA over both g's (bfrag amortized), leaky+pool fused ----
    const f32x4 zc = {0.f, 0.f, 0.f, 0.f};
    const float invd = 1.0f / (float)ND;

    #pragma unroll 1
    for (int gi = 0; gi < 2; ++gi) {
        float s0 = 0.f, s1 = 0.f, s2 = 0.f, s3 = 0.f;

        #pragma unroll 2
        for (int mt = 0; mt < 8; ++mt) {
            const short8 af = *reinterpret_cast<const short8*>(
                &featb[((gi << 9) + (mt << 6) + lane) * 8]);
            {
                f32x4 dd = __builtin_amdgcn_mfma_f32_16x16x32_bf16(af, bfrag[0], zc, 0, 0, 0);
                #pragma unroll
                for (int r = 0; r < 4; ++r)
                    s0 = fmaf(0.505f, dd[r], fmaf(0.495f, fabsf(dd[r]), s0));
            }
            {
                f32x4 dd = __builtin_amdgcn_mfma_f32_16x16x32_bf16(af, bfrag[1], zc, 0, 0, 0);
                #pragma unroll
                for (int r = 0; r < 4; ++r)
                    s1 = fmaf(0.505f, dd[r], fmaf(0.495f, fabsf(dd[r]), s1));
            }
            {
                f32x4 dd = __builtin_amdgcn_mfma_f32_16x16x32_bf16(af, bfrag[2], zc, 0, 0, 0);
                #pragma unroll
                for (int r = 0; r < 4; ++r)
                    s2 = fmaf(0.505f, dd[r], fmaf(0.495f, fabsf(dd[r]), s2));
            }
            {
                f32x4 dd = __builtin_amdgcn_mfma_f32_16x16x32_bf16(af, bfrag[3], zc, 0, 0, 0);
                #pragma unroll
                for (int r = 0; r < 4; ++r)
                    s3 = fmaf(0.505f, dd[r], fmaf(0.495f, fabsf(dd[r]), s3));
            }
        }

        float sv[4] = {s0, s1, s2, s3};
        #pragma unroll
        for (int nt = 0; nt < 4; ++nt) {
            float s4 = sv[nt];
            s4 += __shfl_xor(s4, 16, 64);
            s4 += __shfl_xor(s4, 32, 64);
            if (lane < 16)
                hm_out[(size_t)(g2 + gi) * H + w * 64 + nt * 16 + lane] = s4 * invd;
        }
    }
}

// ---------------------------------------------------------------------------
// Kernel B: layers 1-2, 8 t per block (unchanged)
// ---------------------------------------------------------------------------
__global__ __launch_bounds__(256) void k_l12(
    const float* __restrict__ hm, const float* __restrict__ W1,
    const float* __restrict__ b1, const float* __restrict__ W2,
    const float* __restrict__ b2, float* __restrict__ out)
{
    const int tb  = blockIdx.x * 8;
    const int tid = threadIdx.x;
    __shared__ float hs[8][H];
    __shared__ float h1[8][H];

    {
        const float4* src = reinterpret_cast<const float4*>(hm + (size_t)tb * H);
        float4* dst = reinterpret_cast<float4*>(&hs[0][0]);
        #pragma unroll
        for (int i = 0; i < 2; ++i) dst[tid + i*256] = src[tid + i*256];
    }
    __syncthreads();

    {
        float acc[8];
        const float bb = b1[tid];
        #pragma unroll
        for (int t = 0; t < 8; ++t) acc[t] = bb;
        for (int k = 0; k < H; ++k) {
            const float w = W1[(size_t)k * H + tid];
            #pragma unroll
            for (int t = 0; t < 8; ++t) acc[t] = fmaf(hs[t][k], w, acc[t]);
        }
        #pragma unroll
        for (int t = 0; t < 8; ++t) {
            float a = acc[t];
            h1[t][tid] = (a > 0.f) ? a : 0.01f * a;
        }
    }
    __syncthreads();

    {
        const int n  = tid & 127;
        const int t0 = (tid >> 7) * 4;
        float acc[4];
        const float bb = b2[n];
        #pragma unroll
        for (int t = 0; t < 4; ++t) acc[t] = bb;
        for (int k = 0; k < H; ++k) {
            const float w = W2[(size_t)k * L + n];
            #pragma unroll
            for (int t = 0; t < 4; ++t) acc[t] = fmaf(h1[t0 + t][k], w, acc[t]);
        }
        #pragma unroll
        for (int t = 0; t < 4; ++t)
            out[(size_t)(tb + t0 + t) * L + n] = acc[t];
    }
}

extern "C" void kernel_launch(void* const* d_in, const int* in_sizes, int n_in,
                              void* d_out, int out_size, void* d_ws, size_t ws_size,
                              hipStream_t stream) {
    const float* x0    = (const float*)d_in[0];
    const float* x     = (const float*)d_in[1];
    const int*   Nv    = (const int*)  d_in[2];
    const float* basis = (const float*)d_in[3];
    const float* v     = (const float*)d_in[4];
    const float* W0    = (const float*)d_in[5];
    const float* b0    = (const float*)d_in[6];
    const float* W1    = (const float*)d_in[7];
    const float* b1    = (const float*)d_in[8];
    const float* W2    = (const float*)d_in[9];
    const float* b2    = (const float*)d_in[10];
    float* out = (float*)d_out;
    float* hm  = (float*)d_ws;          // 4096*256*4 = 4 MB

    hipLaunchKernelGGL(k_fused, dim3(4 * NT / 2), dim3(256), 0, stream,
                       x0, x, Nv, basis, v, W0, b0, hm);
    hipLaunchKernelGGL(k_l12, dim3(4 * NT / 8), dim3(256), 0, stream,
                       hm, W1, b1, W2, b2, out);
}

// Round 12
// 48.393 us; speedup vs baseline: 1.5754x; 1.0057x over previous
//
#include <hip/hip_runtime.h>
#include <math.h>

#define EPSF 1e-5f
constexpr int NT  = 1024;
constexpr int ND  = 128;
constexpr int KIN = 19;
constexpr int H   = 256;
constexpr int L   = 128;

typedef __attribute__((ext_vector_type(8))) short short8;
typedef __attribute__((ext_vector_type(4))) float f32x4;

// packed fp32->bf16 (RNE), 2 elements per instruction
static __device__ inline unsigned cvt_pk_bf16(float lo, float hi) {
    unsigned r;
    asm("v_cvt_pk_bf16_f32 %0, %1, %2" : "=v"(r) : "v"(lo), "v"(hi));
    return r;
}

// ---------------------------------------------------------------------------
// Fused kernel A: 2 g's per 256-thread block (2048 blocks = 8192 waves).
// MFMA phase interleaves BOTH g's inside the mt loop: two independent
// ds_read->MFMA->leaky chains per iteration hide each other's latency.
// ---------------------------------------------------------------------------
__global__ __launch_bounds__(256) void k_fused(
    const float* __restrict__ x0, const float* __restrict__ x,
    const int*   __restrict__ Nv, const float* __restrict__ basis,
    const float* __restrict__ v,  const float* __restrict__ W0,
    const float* __restrict__ b0, float* __restrict__ hm_out)
{
    const int tid  = threadIdx.x;
    const int lane = tid & 63;
    const int w    = tid >> 6;            // wave 0..3
    const int g2   = blockIdx.x * 2;

    __shared__ __align__(16) ushort featb[2 * 512 * 8];   // 16 KB
    __shared__ float psh[2][2][3];                        // per-g half-sums

    // ---- Phase 1: features (1 d per thread) ----
    {
        const int sub  = tid >> 7;        // which g of the pair
        const int d    = tid & 127;
        const int g    = g2 + sub;
        const int bidx = g >> 10;

        const float* xp = x + (size_t)g * (ND * 3);
        const float* vp = v + (size_t)g * (ND * 3);
        const float vx = vp[d*3+0], vy = vp[d*3+1], vz = vp[d*3+2];
        const float xx = xp[d*3+0], xy = xp[d*3+1], xz = xp[d*3+2];

        // wave-local 64-sum (each wave covers one 64-d half of one g)
        float sx = vx, sy = vy, sz = vz;
        #pragma unroll
        for (int m = 1; m < 64; m <<= 1) {
            sx += __shfl_xor(sx, m, 64);
            sy += __shfl_xor(sy, m, 64);
            sz += __shfl_xor(sz, m, 64);
        }
        if (lane == 0) {
            psh[sub][w & 1][0] = sx;
            psh[sub][w & 1][1] = sy;
            psh[sub][w & 1][2] = sz;
        }
        __syncthreads();
        const float invd = 1.0f / (float)ND;
        const float v0x = (psh[sub][0][0] + psh[sub][1][0]) * invd;
        const float v0y = (psh[sub][0][1] + psh[sub][1][1]) * invd;
        const float v0z = (psh[sub][0][2] + psh[sub][1][2]) * invd;

        const float* bs = basis + bidx * 9;
        const float b0c = bs[0], b1c = bs[1], b2c = bs[2];
        const float b3c = bs[3], b4c = bs[4], b5c = bs[5];
        const float b6c = bs[6], b7c = bs[7], b8c = bs[8];

        unsigned u0, u1, u2, u3, u4;
        {
            const float ax = x0[g*3+0], ay = x0[g*3+1], az = x0[g*3+2];
            const float x0n = sqrtf(ax*ax + ay*ay + az*az) + EPSF;
            const float v0n = sqrtf(v0x*v0x + v0y*v0y + v0z*v0z) + EPSF;
            const float ix  = 1.f / x0n, iv0 = 1.f / v0n;
            u0 = cvt_pk_bf16(log1pf((float)Nv[g]), x0n);
            u1 = cvt_pk_bf16((ax*b0c + ay*b1c + az*b2c) * ix,
                             (ax*b3c + ay*b4c + az*b5c) * ix);
            u2 = cvt_pk_bf16((ax*b6c + ay*b7c + az*b8c) * ix, v0n);
            u3 = cvt_pk_bf16((v0x*b0c + v0y*b1c + v0z*b2c) * iv0,
                             (v0x*b3c + v0y*b4c + v0z*b5c) * iv0);
            u4 = cvt_pk_bf16((v0x*b6c + v0y*b7c + v0z*b8c) * iv0,
                             (ax*v0x + ay*v0y + az*v0z) * ix * iv0);
        }
        unsigned u5, u6, u7, u8, u9;
        {
            const float cx = vx - v0x, cy = vy - v0y, cz = vz - v0z;
            const float xn = sqrtf(xx*xx + xy*xy + xz*xz) + EPSF;
            const float vn = sqrtf(cx*cx + cy*cy + cz*cz) + EPSF;
            const float ixn = 1.f/xn, ivn = 1.f/vn;
            u5 = cvt_pk_bf16(xn, (xx*b0c + xy*b1c + xz*b2c) * ixn);
            u6 = cvt_pk_bf16((xx*b3c + xy*b4c + xz*b5c) * ixn,
                             (xx*b6c + xy*b7c + xz*b8c) * ixn);
            u7 = cvt_pk_bf16(vn, (cx*b0c + cy*b1c + cz*b2c) * ivn);
            u8 = cvt_pk_bf16((cx*b3c + cy*b4c + cz*b5c) * ivn,
                             (cx*b6c + cy*b7c + cz*b8c) * ivn);
            u9 = cvt_pk_bf16((xx*cx + xy*cy + xz*cz) * ixn * ivn, 1.0f);
        }

        const int mt  = d >> 4;
        const int r16 = d & 15;
        uint4* base = reinterpret_cast<uint4*>(
            &featb[((sub << 9) + (mt << 6) + r16) * 8]);
        base[0]  = uint4{u0, u1, u2, u3};          // kb=0 (k0..7)
        base[16] = uint4{u4, u5, u6, u7};          // kb=1 (k8..15)
        base[32] = uint4{u8, u9, 0u, 0u};          // kb=2 (k16..19,0,0)
        base[48] = uint4{0u, 0u, 0u, 0u};          // kb=3 (zero)
    }
    __syncthreads();

    // ---- Phase 2: B fragments for this wave's 64-col group ----
    short8 bfrag[4];
    {
        const int col16 = lane & 15;
        const int kb    = lane >> 4;
        #pragma unroll
        for (int nt = 0; nt < 4; ++nt) {
            const int col = w * 64 + nt * 16 + col16;
            uint4 pk;
            #pragma unroll
            for (int jj = 0; jj < 4; ++jj) {
                const int k0 = kb * 8 + 2*jj;
                const int k1 = k0 + 1;
                const float a = (k0 < KIN) ? W0[k0 * H + col]
                               : ((k0 == KIN) ? b0[col] : 0.f);
                const float b = (k1 < KIN) ? W0[k1 * H + col]
                               : ((k1 == KIN) ? b0[col] : 0.f);
                (&pk.x)[jj] = cvt_pk_bf16(a, b);
            }
            bfrag[nt] = *reinterpret_cast<short8*>(&pk);
        }
    }

    // ---- MFMA over both g's INTERLEAVED inside the mt loop ----
    const f32x4 zc = {0.f, 0.f, 0.f, 0.f};
    const float invd = 1.0f / (float)ND;

    float a00 = 0.f, a01 = 0.f, a02 = 0.f, a03 = 0.f;   // g0, nt 0..3
    float a10 = 0.f, a11 = 0.f, a12 = 0.f, a13 = 0.f;   // g1, nt 0..3

    #pragma unroll 2
    for (int mt = 0; mt < 8; ++mt) {
        const short8 af0 = *reinterpret_cast<const short8*>(
            &featb[((mt << 6) + lane) * 8]);
        const short8 af1 = *reinterpret_cast<const short8*>(
            &featb[((512 + (mt << 6) + lane)) * 8]);
        {
            f32x4 d0 = __builtin_amdgcn_mfma_f32_16x16x32_bf16(af0, bfrag[0], zc, 0, 0, 0);
            f32x4 d1 = __builtin_amdgcn_mfma_f32_16x16x32_bf16(af1, bfrag[0], zc, 0, 0, 0);
            #pragma unroll
            for (int r = 0; r < 4; ++r) {
                a00 = fmaf(0.505f, d0[r], fmaf(0.495f, fabsf(d0[r]), a00));
                a10 = fmaf(0.505f, d1[r], fmaf(0.495f, fabsf(d1[r]), a10));
            }
        }
        {
            f32x4 d0 = __builtin_amdgcn_mfma_f32_16x16x32_bf16(af0, bfrag[1], zc, 0, 0, 0);
            f32x4 d1 = __builtin_amdgcn_mfma_f32_16x16x32_bf16(af1, bfrag[1], zc, 0, 0, 0);
            #pragma unroll
            for (int r = 0; r < 4; ++r) {
                a01 = fmaf(0.505f, d0[r], fmaf(0.495f, fabsf(d0[r]), a01));
                a11 = fmaf(0.505f, d1[r], fmaf(0.495f, fabsf(d1[r]), a11));
            }
        }
        {
            f32x4 d0 = __builtin_amdgcn_mfma_f32_16x16x32_bf16(af0, bfrag[2], zc, 0, 0, 0);
            f32x4 d1 = __builtin_amdgcn_mfma_f32_16x16x32_bf16(af1, bfrag[2], zc, 0, 0, 0);
            #pragma unroll
            for (int r = 0; r < 4; ++r) {
                a02 = fmaf(0.505f, d0[r], fmaf(0.495f, fabsf(d0[r]), a02));
                a12 = fmaf(0.505f, d1[r], fmaf(0.495f, fabsf(d1[r]), a12));
            }
        }
        {
            f32x4 d0 = __builtin_amdgcn_mfma_f32_16x16x32_bf16(af0, bfrag[3], zc, 0, 0, 0);
            f32x4 d1 = __builtin_amdgcn_mfma_f32_16x16x32_bf16(af1, bfrag[3], zc, 0, 0, 0);
            #pragma unroll
            for (int r = 0; r < 4; ++r) {
                a03 = fmaf(0.505f, d0[r], fmaf(0.495f, fabsf(d0[r]), a03));
                a13 = fmaf(0.505f, d1[r], fmaf(0.495f, fabsf(d1[r]), a13));
            }
        }
    }

    // ---- epilogue: column pool across lane groups, write hm for both g's ----
    {
        float sv0[4] = {a00, a01, a02, a03};
        float sv1[4] = {a10, a11, a12, a13};
        #pragma unroll
        for (int nt = 0; nt < 4; ++nt) {
            float s4 = sv0[nt];
            s4 += __shfl_xor(s4, 16, 64);
            s4 += __shfl_xor(s4, 32, 64);
            float s5 = sv1[nt];
            s5 += __shfl_xor(s5, 16, 64);
            s5 += __shfl_xor(s5, 32, 64);
            if (lane < 16) {
                hm_out[(size_t)(g2 + 0) * H + w * 64 + nt * 16 + lane] = s4 * invd;
                hm_out[(size_t)(g2 + 1) * H + w * 64 + nt * 16 + lane] = s5 * invd;
            }
        }
    }
}

// ---------------------------------------------------------------------------
// Kernel B: layers 1-2, 8 t per block (unchanged)
// ---------------------------------------------------------------------------
__global__ __launch_bounds__(256) void k_l12(
    const float* __restrict__ hm, const float* __restrict__ W1,
    const float* __restrict__ b1, const float* __restrict__ W2,
    const float* __restrict__ b2, float* __restrict__ out)
{
    const int tb  = blockIdx.x * 8;
    const int tid = threadIdx.x;
    __shared__ float hs[8][H];
    __shared__ float h1[8][H];

    {
        const float4* src = reinterpret_cast<const float4*>(hm + (size_t)tb * H);
        float4* dst = reinterpret_cast<float4*>(&hs[0][0]);
        #pragma unroll
        for (int i = 0; i < 2; ++i) dst[tid + i*256] = src[tid + i*256];
    }
    __syncthreads();

    {
        float acc[8];
        const float bb = b1[tid];
        #pragma unroll
        for (int t = 0; t < 8; ++t) acc[t] = bb;
        for (int k = 0; k < H; ++k) {
            const float w = W1[(size_t)k * H + tid];
            #pragma unroll
            for (int t = 0; t < 8; ++t) acc[t] = fmaf(hs[t][k], w, acc[t]);
        }
        #pragma unroll
        for (int t = 0; t < 8; ++t) {
            float a = acc[t];
            h1[t][tid] = (a > 0.f) ? a : 0.01f * a;
        }
    }
    __syncthreads();

    {
        const int n  = tid & 127;
        const int t0 = (tid >> 7) * 4;
        float acc[4];
        const float bb = b2[n];
        #pragma unroll
        for (int t = 0; t < 4; ++t) acc[t] = bb;
        for (int k = 0; k < H; ++k) {
            const float w = W2[(size_t)k * L + n];
            #pragma unroll
            for (int t = 0; t < 4; ++t) acc[t] = fmaf(h1[t0 + t][k], w, acc[t]);
        }
        #pragma unroll
        for (int t = 0; t < 4; ++t)
            out[(size_t)(tb + t0 + t) * L + n] = acc[t];
    }
}

extern "C" void kernel_launch(void* const* d_in, const int* in_sizes, int n_in,
                              void* d_out, int out_size, void* d_ws, size_t ws_size,
                              hipStream_t stream) {
    const float* x0    = (const float*)d_in[0];
    const float* x     = (const float*)d_in[1];
    const int*   Nv    = (const int*)  d_in[2];
    const float* basis = (const float*)d_in[3];
    const float* v     = (const float*)d_in[4];
    const float* W0    = (const float*)d_in[5];
    const float* b0    = (const float*)d_in[6];
    const float* W1    = (const float*)d_in[7];
    const float* b1    = (const float*)d_in[8];
    const float* W2    = (const float*)d_in[9];
    const float* b2    = (const float*)d_in[10];
    float* out = (float*)d_out;
    float* hm  = (float*)d_ws;          // 4096*256*4 = 4 MB

    hipLaunchKernelGGL(k_fused, dim3(4 * NT / 2), dim3(256), 0, stream,
                       x0, x, Nv, basis, v, W0, b0, hm);
    hipLaunchKernelGGL(k_l12, dim3(4 * NT / 8), dim3(256), 0, stream,
                       hm, W1, b1, W2, b2, out);
}